// Round 3
// baseline (701.970 us; speedup 1.0000x reference)
//
#include <hip/hip_runtime.h>
#include <math.h>

// Keep all float arithmetic un-contracted (separate mul/add like the numpy/jax
// f32 reference) so discrete decisions (argmax, top-k order, iou>thr) match.
#pragma clang fp contract(off)

// ---------------- problem constants ----------------
#define BB      8
#define AA      9
#define NCLS    80
#define NTOT    72000      // 57600 + 14400 boxes per image
#define PRE     1000
#define POST    300
#define CAP     4096
#define BCLIP   4.135166556742356f   // log(1000/16)

__device__ __constant__ float c_sizes[9] = {16.f,32.f,64.f,20.f,40.f,80.f,24.f,48.f,96.f};

__device__ inline unsigned fkey(float s) {
    unsigned u = __float_as_uint(s);
    return (u & 0x80000000u) ? ~u : (u | 0x80000000u);
}
__device__ inline float unfkey(unsigned u) {
    return __uint_as_float((u & 0x80000000u) ? (u ^ 0x80000000u) : ~u);
}

// ---------------- kernel A (fused): stream + register argmax ------------------
// One block owns ALL 80 class channels of an 800-cell chunk -> each thread owns
// its 4 cells exclusively: class-max is a register (best, argmax) pair,
// strict-> update (first-max wins = jnp.argmax). Delta channels are NOT read
// here: boxes are decoded only for the top-1000 in k_select. Histogram is a
// flat 16-bit fkey histogram (65536 bins/image) via global atomics.
template<int BR>
__device__ inline void fused_impl(int bx, const float* __restrict__ data,
    float* __restrict__ scores, float* __restrict__ cls,
    unsigned* __restrict__ fhist16)
{
    constexpr int ROWF4  = BR ? 400 : 1600;   // channel row length in float4
    constexpr int NQ     = BR ? 2 : 8;        // chunks per row (200 f4 each)

    int slab = bx / NQ;
    int q    = bx - slab * NQ;
    int b = slab / 9, a = slab - (slab / 9) * 9;
    int tid = threadIdx.x;
    if (tid >= 200) return;

    const float4* d4 = (const float4*)data;
    size_t rowbase = (size_t)(b * 756 + a * 84) * ROWF4 + q * 200;

    float best[4];
    int   bc[4];
    #pragma unroll
    for (int k = 0; k < 4; k++) { best[k] = -INFINITY; bc[k] = 0; }

    // class channels 4..83, batches of 8 (8 loads in flight)
    for (int c0 = 4; c0 < 84; c0 += 8) {
        float4 v[8];
        #pragma unroll
        for (int u = 0; u < 8; u++)
            v[u] = d4[rowbase + (size_t)(c0 + u) * ROWF4 + tid];
        #pragma unroll
        for (int u = 0; u < 8; u++) {
            int c = c0 + u - 4;
            float s0[4];
            *(float4*)s0 = v[u];
            #pragma unroll
            for (int k = 0; k < 4; k++)
                if (s0[k] > best[k]) { best[k] = s0[k]; bc[k] = c; }
        }
    }

    int ml0 = q * 800 + tid * 4;
    size_t obase = (size_t)b * NTOT + (BR ? (57600 + a * 1600) : (a * 6400));
    size_t o4 = (obase + ml0) >> 2;
    ((float4*)scores)[o4] = make_float4(best[0], best[1], best[2], best[3]);
    ((float4*)cls)[o4]    = make_float4((float)bc[0], (float)bc[1],
                                        (float)bc[2], (float)bc[3]);
    unsigned* hb = fhist16 + (size_t)b * 65536;
    #pragma unroll
    for (int k = 0; k < 4; k++)
        atomicAdd(&hb[fkey(best[k]) >> 16], 1u);
}

__global__ __launch_bounds__(256) void k_fused(
    const float* __restrict__ data0, const float* __restrict__ data1,
    float* __restrict__ scores, float* __restrict__ cls,
    unsigned* __restrict__ fhist16)
{
    int bx = blockIdx.x;
    if (bx < 576) fused_impl<0>(bx, data0, scores, cls, fhist16);
    else          fused_impl<1>(bx - 576, data1, scores, cls, fhist16);
}

// ---------------- kernel: two-level scan of flat 16-bit histogram -> T --------
__global__ __launch_bounds__(256) void k_thr(const unsigned* __restrict__ fhist16,
                                             unsigned* __restrict__ T)
{
    __shared__ unsigned S[256];
    __shared__ unsigned sC, sCa;
    int b = blockIdx.x, tid = threadIdx.x;

    // level 1: each thread sums 256 bins
    const uint4* h4 = (const uint4*)(fhist16 + (size_t)b * 65536 + tid * 256);
    unsigned s = 0;
    #pragma unroll 8
    for (int i = 0; i < 64; i++) { uint4 v = h4[i]; s += v.x + v.y + v.z + v.w; }
    S[tid] = s;
    __syncthreads();
    for (int off = 1; off < 256; off <<= 1) {   // suffix sum
        unsigned v = S[tid] + ((tid + off < 256) ? S[tid + off] : 0u);
        __syncthreads();
        S[tid] = v;
        __syncthreads();
    }
    if (S[tid] >= (unsigned)PRE && (tid == 255 || S[tid + 1] < (unsigned)PRE)) {
        sC  = tid;
        sCa = (tid == 255) ? 0u : S[tid + 1];
    }
    __syncthreads();
    unsigned C = sC, ca = sCa;

    // level 2: bins within coarse block C
    S[tid] = fhist16[(size_t)b * 65536 + C * 256 + tid];
    __syncthreads();
    for (int off = 1; off < 256; off <<= 1) {
        unsigned v = S[tid] + ((tid + off < 256) ? S[tid + off] : 0u);
        __syncthreads();
        S[tid] = v;
        __syncthreads();
    }
    if (ca + S[tid] >= (unsigned)PRE && (tid == 255 || ca + S[tid + 1] < (unsigned)PRE))
        T[b] = C * 256 + (unsigned)tid;
}

// ---------------- kernel: compact candidates >= threshold bucket --------------
__global__ __launch_bounds__(256) void k_compact(const float* __restrict__ scores,
                                                 const unsigned* __restrict__ T,
                                                 unsigned* __restrict__ cnt,
                                                 unsigned long long* __restrict__ cand)
{
    int m4 = blockIdx.x * 256 + threadIdx.x;
    int b = blockIdx.y;
    if (m4 >= NTOT / 4) return;
    float sv[4];
    *(float4*)sv = ((const float4*)(scores + (size_t)b * NTOT))[m4];
    unsigned Tb = T[b];
    #pragma unroll
    for (int k = 0; k < 4; k++) {
        unsigned u = fkey(sv[k]);
        if ((u >> 16) >= Tb) {
            int m = m4 * 4 + k;
            int n;
            if (m < 57600) { int a = m / 6400; int hw = m - a * 6400; n = hw * 9 + a; }
            else { int mm = m - 57600; int a = mm / 1600; int hw = mm - a * 1600; n = 57600 + hw * 9 + a; }
            unsigned pos = atomicAdd(&cnt[b], 1u);
            if (pos < CAP)
                cand[(size_t)b * CAP + pos] = ((unsigned long long)u << 32) | (unsigned)(~(unsigned)n);
        }
    }
}

// ---------------- kernel: sort + decode-gather + mask + NMS + output ----------
// One block per image (1024 threads). Phases:
//  P1 bitonic sort of candidate keys in LDS (descending taken from top end).
//  P2 top-1000: decode boxes from raw input deltas (4 scattered loads each),
//     scores from key, cls gather -> LDS arrays.
//  P3 transposed suppressor mask (thread j owns column j), written to global
//     maskT (L2-hot, read back by the same block).
//  P4 wave-0 greedy NMS: ballot/ffs serial chain, zero cross-lane data moves.
//  P5 all threads: rank via popcounts of kws, direct output write.
__global__ __launch_bounds__(1024) void k_select(
    const unsigned long long* __restrict__ cand, const unsigned* __restrict__ cnt,
    const float* __restrict__ cls,
    const float* __restrict__ data0, const float* __restrict__ data1,
    unsigned long long* __restrict__ maskT, float* __restrict__ out)
{
    __shared__ unsigned long long keys[CAP];
    __shared__ float4 sbx[1024];
    __shared__ float  ssc[1024];
    __shared__ float  scl[1024];
    __shared__ unsigned long long kws[16];

    int b = blockIdx.x, tid = threadIdx.x;

    // ---- P1: bitonic sort ----
    int c = min((int)cnt[b], CAP);
    int P = 1024;
    while (P < c) P <<= 1;
    for (int i = tid; i < P; i += 1024)
        keys[i] = (i < c) ? cand[(size_t)b * CAP + i] : 0ULL;

    for (int k2 = 2; k2 <= P; k2 <<= 1)
        for (int j = k2 >> 1; j > 0; j >>= 1) {
            __syncthreads();
            for (int i = tid; i < P; i += 1024) {
                int l = i ^ j;
                if (l > i) {
                    unsigned long long x = keys[i], y = keys[l];
                    bool up = ((i & k2) == 0);
                    if ((x > y) == up) { keys[i] = y; keys[l] = x; }
                }
            }
        }
    __syncthreads();

    // ---- P2: decode + gather top-1000 into LDS ----
    if (tid < PRE) {
        unsigned long long key = keys[P - 1 - tid];       // descending
        int n = (int)~(unsigned)(key & 0xFFFFFFFFu);
        int a, hw, W, STRIDE, m;
        const float* dsrc;
        size_t rstride;
        if (n < 57600) {
            hw = n / 9; a = n - hw * 9; m = a * 6400 + hw;
            W = 80; STRIDE = 8; dsrc = data0; rstride = 6400;
        } else {
            int n2 = n - 57600;
            hw = n2 / 9; a = n2 - hw * 9; m = 57600 + a * 1600 + hw;
            W = 40; STRIDE = 16; dsrc = data1; rstride = 1600;
        }
        size_t dbase = (size_t)(b * 756 + a * 84) * rstride + hw;
        float dx = dsrc[dbase];
        float dy = dsrc[dbase + rstride];
        float dw = dsrc[dbase + 2 * rstride];
        float dh = dsrc[dbase + 3 * rstride];

        float sz = c_sizes[a];
        int h = hw / W, w = hw - h * W;
        float cy = (h + 0.5f) * (float)STRIDE;
        float cx = (w + 0.5f) * (float)STRIDE;
        float pcx = dx * sz + cx;
        float pcy = dy * sz + cy;
        float pw  = expf(fminf(dw, BCLIP)) * sz;
        float ph  = expf(fminf(dh, BCLIP)) * sz;
        float x1 = fminf(fmaxf(pcx - 0.5f * pw, 0.f), 640.f);
        float y1 = fminf(fmaxf(pcy - 0.5f * ph, 0.f), 640.f);
        float x2 = fminf(fmaxf(pcx + 0.5f * pw, 0.f), 640.f);
        float y2 = fminf(fmaxf(pcy + 0.5f * ph, 0.f), 640.f);

        sbx[tid] = make_float4(x1, y1, x2, y2);
        ssc[tid] = unfkey((unsigned)(key >> 32));
        scl[tid] = cls[(size_t)b * NTOT + m];
    } else {
        sbx[tid] = make_float4(0.f, 0.f, 0.f, 0.f);
        ssc[tid] = 0.f;
        scl[tid] = 0.f;
    }
    __syncthreads();

    // ---- P3: transposed suppressor mask (column j, suppressor chunks w) ----
    unsigned long long* maskTb = maskT + (size_t)b * 16 * 1024;
    {
        int j = tid;
        float4 bj = sbx[j];
        float sj = ssc[j];
        float areaj = (bj.z - bj.x) * (bj.w - bj.y);
        #pragma unroll
        for (int w = 0; w < 16; w++) {
            unsigned long long bits = 0;
            if (j < PRE && w * 64 < j) {
                int iend = min(64, j - w * 64);   // suppressors have i < j
                for (int ii = 0; ii < iend; ii++) {
                    float4 bi = sbx[w * 64 + ii];
                    float ix1 = fmaxf(bi.x, bj.x), iy1 = fmaxf(bi.y, bj.y);
                    float ix2 = fminf(bi.z, bj.z), iy2 = fminf(bi.w, bj.w);
                    float iw = fmaxf(ix2 - ix1, 0.f), ih = fmaxf(iy2 - iy1, 0.f);
                    float inter = iw * ih;
                    float areai = (bi.z - bi.x) * (bi.w - bi.y);
                    float iou = inter / (areai + areaj - inter + 1e-9f);
                    if (iou > 0.5f && ssc[w * 64 + ii] > sj) bits |= 1ull << ii;
                }
            }
            maskTb[(w << 10) + j] = bits;
        }
    }
    __syncthreads();   // drains vmcnt: mask visible to wave 0 via same-XCD L2

    // ---- P4: wave-0 greedy NMS (ballot/ffs only) ----
    if (tid < 64) {
        int lane = tid;
        unsigned validbits = 0;
        #pragma unroll
        for (int cc = 0; cc < 16; cc++) {
            int r = cc * 64 + lane;
            bool v = false;
            if (r < PRE) {
                float sc = ssc[r];
                float4 bbx = sbx[r];
                v = (sc >= 0.05f) && (bbx.x < bbx.z) && (bbx.y < bbx.w);
            }
            validbits |= (v ? 1u : 0u) << cc;
        }

        unsigned long long keptw[16];
        #pragma unroll
        for (int cc = 0; cc < 16; cc++) {
            unsigned long long acc = 0, col = 0;
            #pragma unroll
            for (int w = 0; w <= cc; w++) {
                unsigned long long m = maskTb[(w << 10) + cc * 64 + lane];
                if (w < cc) acc |= m & keptw[w];
                else        col = m;
            }
            bool alive = (((validbits >> cc) & 1u) != 0u) && (acc == 0ULL);

            unsigned long long ab = __ballot(alive);
            unsigned long long kw = 0;
            while (ab) {
                int f = __ffsll((unsigned long long)ab) - 1;
                kw |= 1ULL << f;
                alive = alive && (lane != f) && (((col >> f) & 1ULL) == 0ULL);
                ab = __ballot(alive);
            }
            keptw[cc] = kw;
        }
        if (lane == 0) {
            #pragma unroll
            for (int w = 0; w < 16; w++) kws[w] = keptw[w];
        }
    }
    __syncthreads();

    // ---- P5: rank + output (one thread per pre-NMS slot) ----
    float* ob = out;                       // [8][300][4]
    float* os = out + BB * POST * 4;       // [8][300]
    float* oc = os + BB * POST;            // [8][300]

    int nk = 0;
    {
        int w = tid >> 6;
        int rank = 0;
        #pragma unroll
        for (int ww = 0; ww < 16; ww++) {
            int p = __popcll(kws[ww]);
            if (ww < w) rank += p;
            nk += p;
        }
        if (tid < PRE) {
            unsigned long long kw = kws[w];
            if ((kw >> (tid & 63)) & 1ULL) {
                rank += __popcll(kw & ((1ULL << (tid & 63)) - 1ULL));
                if (rank < POST) {
                    ((float4*)ob)[b * POST + rank] = sbx[tid];
                    os[b * POST + rank] = ssc[tid];
                    oc[b * POST + rank] = scl[tid];
                }
            }
        }
    }
    if (tid >= nk && tid < POST) {
        ((float4*)ob)[b * POST + tid] = make_float4(0.f, 0.f, 0.f, 0.f);
        os[b * POST + tid] = 0.f;
        oc[b * POST + tid] = 0.f;
    }
}

// ---------------- launch ----------------
extern "C" void kernel_launch(void* const* d_in, const int* in_sizes, int n_in,
                              void* d_out, int out_size, void* d_ws, size_t ws_size,
                              hipStream_t stream)
{
    const float* data0 = (const float*)d_in[0];
    const float* data1 = (const float*)d_in[2];
    for (int i = 0; i < n_in; i++) {
        if (in_sizes[i] == 8 * 756 * 6400) data0 = (const float*)d_in[i];
        else if (in_sizes[i] == 8 * 756 * 1600) data1 = (const float*)d_in[i];
    }

    char* ws = (char*)d_ws;
    size_t off = 0;
    auto alloc = [&](size_t bytes) -> char* {
        char* p = ws + off;
        off = (off + bytes + 255) & ~(size_t)255;
        return p;
    };

    float* scores  = (float*)alloc((size_t)BB * NTOT * 4);
    float* cls     = (float*)alloc((size_t)BB * NTOT * 4);
    // zero-init group (contiguous): cnt(256B pad) + fhist16(2MB)
    unsigned* cnt     = (unsigned*)alloc(BB * 4);
    unsigned* fhist16 = (unsigned*)alloc((size_t)BB * 65536 * 4);
    unsigned* T    = (unsigned*)alloc(BB * 4);
    unsigned long long* cand  = (unsigned long long*)alloc((size_t)BB * CAP * 8);
    unsigned long long* maskT = (unsigned long long*)alloc((size_t)BB * 16 * 1024 * 8);

    (void)hipMemsetAsync(cnt, 0, 256 + (size_t)BB * 65536 * 4, stream);

    k_fused<<<720, 256, 0, stream>>>(data0, data1, scores, cls, fhist16);

    k_thr<<<BB, 256, 0, stream>>>(fhist16, T);

    dim3 gf((NTOT / 4 + 255) / 256, BB);
    k_compact<<<gf, 256, 0, stream>>>(scores, T, cnt, cand);

    k_select<<<BB, 1024, 0, stream>>>(cand, cnt, cls, data0, data1, maskT,
                                      (float*)d_out);
}

// Round 4
// 442.439 us; speedup vs baseline: 1.5866x; 1.5866x over previous
//
#include <hip/hip_runtime.h>
#include <math.h>

// Keep all float arithmetic un-contracted (separate mul/add like the numpy/jax
// f32 reference) so discrete decisions (argmax, top-k order, iou>thr) match.
#pragma clang fp contract(off)

// ---------------- problem constants ----------------
#define BB      8
#define AA      9
#define NCLS    80
#define NTOT    72000      // 57600 + 14400 boxes per image
#define PRE     1000
#define POST    300
#define CAP     4096
#define BCLIP   4.135166556742356f   // log(1000/16)

__device__ __constant__ float c_sizes[9] = {16.f,32.f,64.f,20.f,40.f,80.f,24.f,48.f,96.f};

__device__ inline unsigned fkey(float s) {
    unsigned u = __float_as_uint(s);
    return (u & 0x80000000u) ? ~u : (u | 0x80000000u);
}
__device__ inline float unfkey(unsigned u) {
    return __uint_as_float((u & 0x80000000u) ? (u ^ 0x80000000u) : ~u);
}

// ---------------- kernel A (fused): stream + register argmax ------------------
// One block owns ALL 80 class channels of an 800-cell chunk -> each thread owns
// its 4 cells exclusively: class-max is a register (best, argmax) pair,
// strict-> update (first-max wins = jnp.argmax). Delta channels are NOT read
// here: boxes are decoded only for the top-1000 at gather time (k_sort).
// Coarse 8-bit histogram aggregated in LDS, flushed once per block.
template<int BR>
__device__ inline void fused_impl(int bx, const float* __restrict__ data,
    float* __restrict__ scores, float* __restrict__ cls,
    unsigned* __restrict__ chist, unsigned* lh)
{
    constexpr int ROWF4  = BR ? 400 : 1600;   // channel row length in float4
    constexpr int NQ     = BR ? 2 : 8;        // chunks per row (200 f4 each)

    int slab = bx / NQ;
    int q    = bx - slab * NQ;
    int b = slab / 9, a = slab - (slab / 9) * 9;
    int tid = threadIdx.x;

    if (tid < 200) {
        const float4* d4 = (const float4*)data;
        size_t rowbase = (size_t)(b * 756 + a * 84) * ROWF4 + q * 200;

        float best[4];
        int   bc[4];
        #pragma unroll
        for (int k = 0; k < 4; k++) { best[k] = -INFINITY; bc[k] = 0; }

        // class channels 4..83, batches of 8 (8 loads in flight)
        for (int c0 = 4; c0 < 84; c0 += 8) {
            float4 v[8];
            #pragma unroll
            for (int u = 0; u < 8; u++)
                v[u] = d4[rowbase + (size_t)(c0 + u) * ROWF4 + tid];
            #pragma unroll
            for (int u = 0; u < 8; u++) {
                int c = c0 + u - 4;
                float s0[4];
                *(float4*)s0 = v[u];
                #pragma unroll
                for (int k = 0; k < 4; k++)
                    if (s0[k] > best[k]) { best[k] = s0[k]; bc[k] = c; }
            }
        }

        int ml0 = q * 800 + tid * 4;
        size_t obase = (size_t)b * NTOT + (BR ? (57600 + a * 1600) : (a * 6400));
        size_t o4 = (obase + ml0) >> 2;
        ((float4*)scores)[o4] = make_float4(best[0], best[1], best[2], best[3]);
        ((float4*)cls)[o4]    = make_float4((float)bc[0], (float)bc[1],
                                            (float)bc[2], (float)bc[3]);
        #pragma unroll
        for (int k = 0; k < 4; k++)
            atomicAdd(&lh[fkey(best[k]) >> 24], 1u);
    }
    __syncthreads();
    if (lh[threadIdx.x]) atomicAdd(&chist[b * 256 + threadIdx.x], lh[threadIdx.x]);
}

__global__ __launch_bounds__(256) void k_fused(
    const float* __restrict__ data0, const float* __restrict__ data1,
    float* __restrict__ scores, float* __restrict__ cls,
    unsigned* __restrict__ chist)
{
    __shared__ unsigned lh[256];
    lh[threadIdx.x] = 0;
    __syncthreads();
    int bx = blockIdx.x;
    if (bx < 576) fused_impl<0>(bx, data0, scores, cls, chist, lh);
    else          fused_impl<1>(bx - 576, data1, scores, cls, chist, lh);
}

// ---------------- kernel C2: coarse scan (folded) + fine histogram ------------
__global__ __launch_bounds__(256) void k_fine(const float* __restrict__ scores,
                                              const unsigned* __restrict__ chist,
                                              unsigned* __restrict__ fhist)
{
    __shared__ unsigned S[256];
    __shared__ unsigned lh[256];
    __shared__ unsigned sC;
    int tid = threadIdx.x, b = blockIdx.y;
    S[tid]  = chist[b * 256 + tid];
    lh[tid] = 0;
    __syncthreads();
    for (int off = 1; off < 256; off <<= 1) {   // suffix sum
        unsigned v = S[tid] + ((tid + off < 256) ? S[tid + off] : 0u);
        __syncthreads();
        S[tid] = v;
        __syncthreads();
    }
    if (S[tid] >= (unsigned)PRE && (tid == 255 || S[tid + 1] < (unsigned)PRE)) sC = tid;
    __syncthreads();
    unsigned C = sC;

    int m4 = blockIdx.x * 256 + tid;
    if (m4 < NTOT / 4) {
        float sv[4];
        *(float4*)sv = ((const float4*)(scores + (size_t)b * NTOT))[m4];
        #pragma unroll
        for (int k = 0; k < 4; k++) {
            unsigned u = fkey(sv[k]);
            if ((u >> 24) == C) atomicAdd(&lh[(u >> 16) & 0xFF], 1u);
        }
    }
    __syncthreads();
    if (lh[tid]) atomicAdd(&fhist[b * 256 + tid], lh[tid]);
}

// ---------------- kernel: both scans (folded) + compact >= threshold ----------
__global__ __launch_bounds__(256) void k_compact(const float* __restrict__ scores,
                                                 const unsigned* __restrict__ chist,
                                                 const unsigned* __restrict__ fhist,
                                                 unsigned* __restrict__ cnt,
                                                 unsigned long long* __restrict__ cand)
{
    __shared__ unsigned S[256];
    __shared__ unsigned sC, sCa, sT;
    int tid = threadIdx.x, b = blockIdx.y;

    S[tid] = chist[b * 256 + tid];
    __syncthreads();
    for (int off = 1; off < 256; off <<= 1) {
        unsigned v = S[tid] + ((tid + off < 256) ? S[tid + off] : 0u);
        __syncthreads();
        S[tid] = v;
        __syncthreads();
    }
    if (S[tid] >= (unsigned)PRE && (tid == 255 || S[tid + 1] < (unsigned)PRE)) {
        sC  = tid;
        sCa = (tid == 255) ? 0u : S[tid + 1];
    }
    __syncthreads();
    unsigned C = sC, ca = sCa;
    S[tid] = fhist[b * 256 + tid];
    __syncthreads();
    for (int off = 1; off < 256; off <<= 1) {
        unsigned v = S[tid] + ((tid + off < 256) ? S[tid + off] : 0u);
        __syncthreads();
        S[tid] = v;
        __syncthreads();
    }
    if (ca + S[tid] >= (unsigned)PRE && (tid == 255 || ca + S[tid + 1] < (unsigned)PRE))
        sT = (C << 8) | (unsigned)tid;
    __syncthreads();
    unsigned Tb = sT;

    int m4 = blockIdx.x * 256 + tid;
    if (m4 >= NTOT / 4) return;
    float sv[4];
    *(float4*)sv = ((const float4*)(scores + (size_t)b * NTOT))[m4];
    #pragma unroll
    for (int k = 0; k < 4; k++) {
        unsigned u = fkey(sv[k]);
        if ((u >> 16) >= Tb) {
            int m = m4 * 4 + k;
            int n;
            if (m < 57600) { int a = m / 6400; int hw = m - a * 6400; n = hw * 9 + a; }
            else { int mm = m - 57600; int a = mm / 1600; int hw = mm - a * 1600; n = 57600 + hw * 9 + a; }
            unsigned pos = atomicAdd(&cnt[b], 1u);
            if (pos < CAP)
                cand[(size_t)b * CAP + pos] = ((unsigned long long)u << 32) | (unsigned)(~(unsigned)n);
        }
    }
}

// ---------------- kernel: per-image bitonic sort + decode-gather --------------
// Top-1000 boxes are decoded here from the raw input deltas (4 scattered 4B
// loads each) -- the full 72000-box decode/boxes buffer no longer exists.
__global__ __launch_bounds__(1024) void k_sort(
    const unsigned long long* __restrict__ cand, const unsigned* __restrict__ cnt,
    const float* __restrict__ cls,
    const float* __restrict__ data0, const float* __restrict__ data1,
    float* __restrict__ sboxes, float* __restrict__ sscores, float* __restrict__ scls)
{
    __shared__ unsigned long long keys[CAP];
    int b = blockIdx.x, tid = threadIdx.x;
    int c = min((int)cnt[b], CAP);
    int P = 1024;
    while (P < c) P <<= 1;
    for (int i = tid; i < P; i += 1024)
        keys[i] = (i < c) ? cand[(size_t)b * CAP + i] : 0ULL;

    for (int k2 = 2; k2 <= P; k2 <<= 1)
        for (int j = k2 >> 1; j > 0; j >>= 1) {
            __syncthreads();
            for (int i = tid; i < P; i += 1024) {
                int l = i ^ j;
                if (l > i) {
                    unsigned long long x = keys[i], y = keys[l];
                    bool up = ((i & k2) == 0);
                    if ((x > y) == up) { keys[i] = y; keys[l] = x; }
                }
            }
        }
    __syncthreads();

    if (tid < PRE) {
        unsigned long long key = keys[P - 1 - tid];       // descending
        int n = (int)~(unsigned)(key & 0xFFFFFFFFu);
        int a, hw, W, STRIDE, m;
        const float* dsrc;
        size_t rstride;
        if (n < 57600) {
            hw = n / 9; a = n - hw * 9; m = a * 6400 + hw;
            W = 80; STRIDE = 8; dsrc = data0; rstride = 6400;
        } else {
            int n2 = n - 57600;
            hw = n2 / 9; a = n2 - hw * 9; m = 57600 + a * 1600 + hw;
            W = 40; STRIDE = 16; dsrc = data1; rstride = 1600;
        }
        size_t dbase = (size_t)(b * 756 + a * 84) * rstride + hw;
        float dx = dsrc[dbase];
        float dy = dsrc[dbase + rstride];
        float dw = dsrc[dbase + 2 * rstride];
        float dh = dsrc[dbase + 3 * rstride];

        float sz = c_sizes[a];
        int h = hw / W, w = hw - h * W;
        float cy = (h + 0.5f) * (float)STRIDE;
        float cx = (w + 0.5f) * (float)STRIDE;
        float pcx = dx * sz + cx;
        float pcy = dy * sz + cy;
        float pw  = expf(fminf(dw, BCLIP)) * sz;
        float ph  = expf(fminf(dh, BCLIP)) * sz;
        float x1 = fminf(fmaxf(pcx - 0.5f * pw, 0.f), 640.f);
        float y1 = fminf(fmaxf(pcy - 0.5f * ph, 0.f), 640.f);
        float x2 = fminf(fmaxf(pcx + 0.5f * pw, 0.f), 640.f);
        float y2 = fminf(fmaxf(pcy + 0.5f * ph, 0.f), 640.f);

        ((float4*)sboxes)[b * 1024 + tid] = make_float4(x1, y1, x2, y2);
        sscores[b * 1024 + tid] = unfkey((unsigned)(key >> 32));
        scls[b * 1024 + tid] = cls[(size_t)b * NTOT + m];
    }
}

// ---------------- kernel: IN-suppressor bitmask, transposed layout -------------
// maskT[(b*16 + w)*1024 + j] = bits over ii: box i = w*64+ii suppresses box j
// (i < j, iou > NMS_THR, s_i > s_j).  Lane-contiguous in j: coalesced reads and
// zero cross-lane shuffles in k_nms.
__global__ __launch_bounds__(1024) void k_mask(const float* __restrict__ sboxes,
                                               const float* __restrict__ sscores,
                                               unsigned long long* __restrict__ maskT)
{
    __shared__ float4 bx[64];
    __shared__ float  sl[64];
    int b = blockIdx.y, w = blockIdx.x, tid = threadIdx.x;
    if (tid < 64) {
        int i = w * 64 + tid;
        bx[tid] = ((const float4*)sboxes)[b * 1024 + i];
        sl[tid] = sscores[b * 1024 + i];
    }
    __syncthreads();
    int j = tid;
    unsigned long long* dst = &maskT[((size_t)(b * 16) + w) * 1024 + j];
    if (j >= PRE || w * 64 >= j) { *dst = 0ULL; return; }

    float4 bj = ((const float4*)sboxes)[b * 1024 + j];
    float sj = sscores[b * 1024 + j];
    float areaj = (bj.z - bj.x) * (bj.w - bj.y);
    unsigned long long bits = 0;
    int iend = min(64, j - w * 64);          // suppressors must have i < j
    for (int ii = 0; ii < iend; ii++) {
        float4 bi = bx[ii];
        float ix1 = fmaxf(bi.x, bj.x), iy1 = fmaxf(bi.y, bj.y);
        float ix2 = fminf(bi.z, bj.z), iy2 = fminf(bi.w, bj.w);
        float iw = fmaxf(ix2 - ix1, 0.f), ih = fmaxf(iy2 - iy1, 0.f);
        float inter = iw * ih;
        float areai = (bi.z - bi.x) * (bi.w - bi.y);
        float iou = inter / (areai + areaj - inter + 1e-9f);
        if (iou > 0.5f && sl[ii] > sj) bits |= 1ull << ii;
    }
    *dst = bits;
}

// ---------------- kernel: shuffle-free greedy NMS + output (1 wave / image) ---
__global__ __launch_bounds__(64) void k_nms(const unsigned long long* __restrict__ maskT,
                                            const float* __restrict__ sboxes,
                                            const float* __restrict__ sscores,
                                            const float* __restrict__ scls,
                                            float* __restrict__ out)
{
    int b = blockIdx.x, lane = threadIdx.x;
    const unsigned long long* base = maskT + (size_t)b * 16 * 1024;

    // per-lane validity bit for each chunk (bit c = box c*64+lane valid)
    unsigned validbits = 0;
    #pragma unroll
    for (int c = 0; c < 16; c++) {
        int r = c * 64 + lane;
        bool v = false;
        if (r < PRE) {
            float sc = sscores[b * 1024 + r];
            float4 bbx = ((const float4*)sboxes)[b * 1024 + r];
            v = (sc >= 0.05f) && (bbx.x < bbx.z) && (bbx.y < bbx.w);
        }
        validbits |= (v ? 1u : 0u) << c;
    }

    unsigned long long keptw[16];
    #pragma unroll
    for (int c = 0; c < 16; c++) {
        unsigned long long acc = 0, col = 0;
        #pragma unroll
        for (int w = 0; w <= c; w++) {
            unsigned long long m = base[(w << 10) + c * 64 + lane];
            if (w < c) acc |= m & keptw[w];   // suppressed by an earlier kept box?
            else       col = m;               // intra-chunk suppressor column
        }
        bool alive = (((validbits >> c) & 1u) != 0u) && (acc == 0ULL);

        unsigned long long ab = __ballot(alive);
        unsigned long long kw = 0;
        while (ab) {
            int f = __ffsll((unsigned long long)ab) - 1;   // first alive -> kept
            kw |= 1ULL << f;
            alive = alive && (lane != f) && (((col >> f) & 1ULL) == 0ULL);
            ab = __ballot(alive);
        }
        keptw[c] = kw;
    }

    __shared__ unsigned long long kws[16];
    __shared__ int pfx[17];
    if (lane == 0) {
        int s = 0;
        #pragma unroll
        for (int w = 0; w < 16; w++) {
            kws[w] = keptw[w];
            pfx[w] = s;
            s += __popcll(keptw[w]);
        }
        pfx[16] = s;
    }
    __syncthreads();
    int nk = pfx[16];

    float* ob = out;                       // [8][300][4]
    float* os = out + BB * POST * 4;       // [8][300]
    float* oc = os + BB * POST;            // [8][300]

    for (int r = lane; r < PRE; r += 64) {
        int w = r >> 6;
        unsigned long long kw = kws[w];
        if ((kw >> (r & 63)) & 1ULL) {
            int rank = pfx[w] + __popcll(kw & ((1ULL << (r & 63)) - 1ULL));
            if (rank < POST) {
                ((float4*)ob)[b * POST + rank] = ((const float4*)sboxes)[b * 1024 + r];
                os[b * POST + rank] = sscores[b * 1024 + r];
                oc[b * POST + rank] = scls[b * 1024 + r];
            }
        }
    }
    for (int p = nk + lane; p < POST; p += 64) {
        ((float4*)ob)[b * POST + p] = make_float4(0.f, 0.f, 0.f, 0.f);
        os[b * POST + p] = 0.f;
        oc[b * POST + p] = 0.f;
    }
}

// ---------------- launch ----------------
extern "C" void kernel_launch(void* const* d_in, const int* in_sizes, int n_in,
                              void* d_out, int out_size, void* d_ws, size_t ws_size,
                              hipStream_t stream)
{
    const float* data0 = (const float*)d_in[0];
    const float* data1 = (const float*)d_in[2];
    for (int i = 0; i < n_in; i++) {
        if (in_sizes[i] == 8 * 756 * 6400) data0 = (const float*)d_in[i];
        else if (in_sizes[i] == 8 * 756 * 1600) data1 = (const float*)d_in[i];
    }

    char* ws = (char*)d_ws;
    size_t off = 0;
    auto alloc = [&](size_t bytes) -> char* {
        char* p = ws + off;
        off = (off + bytes + 255) & ~(size_t)255;
        return p;
    };

    float* scores  = (float*)alloc((size_t)BB * NTOT * 4);
    float* cls     = (float*)alloc((size_t)BB * NTOT * 4);
    // zero-init group (contiguous): cnt(256B pad) + chist(8K) + fhist(8K)
    unsigned* cnt   = (unsigned*)alloc(BB * 4);
    unsigned* chist = (unsigned*)alloc(BB * 256 * 4);
    unsigned* fhist = (unsigned*)alloc(BB * 256 * 4);
    unsigned long long* cand = (unsigned long long*)alloc((size_t)BB * CAP * 8);
    float* sboxes  = (float*)alloc((size_t)BB * 1024 * 4 * 4);
    float* sscores = (float*)alloc((size_t)BB * 1024 * 4);
    float* scls    = (float*)alloc((size_t)BB * 1024 * 4);
    unsigned long long* maskT = (unsigned long long*)alloc((size_t)BB * 16 * 1024 * 8);

    (void)hipMemsetAsync(cnt, 0, 256 + 2 * (size_t)BB * 256 * 4, stream);

    k_fused<<<720, 256, 0, stream>>>(data0, data1, scores, cls, chist);

    dim3 gf((NTOT / 4 + 255) / 256, BB);
    k_fine<<<gf, 256, 0, stream>>>(scores, chist, fhist);

    k_compact<<<gf, 256, 0, stream>>>(scores, chist, fhist, cnt, cand);

    k_sort<<<BB, 1024, 0, stream>>>(cand, cnt, cls, data0, data1,
                                    sboxes, sscores, scls);

    dim3 g5(16, BB);
    k_mask<<<g5, 1024, 0, stream>>>(sboxes, sscores, maskT);

    k_nms<<<BB, 64, 0, stream>>>(maskT, sboxes, sscores, scls, (float*)d_out);
}

// Round 6
// 410.485 us; speedup vs baseline: 1.7101x; 1.0778x over previous
//
#include <hip/hip_runtime.h>
#include <math.h>

// Keep all float arithmetic un-contracted (separate mul/add like the numpy/jax
// f32 reference) so discrete decisions (argmax, top-k order, iou>thr) match.
#pragma clang fp contract(off)

// ---------------- problem constants ----------------
#define BB      8
#define AA      9
#define NCLS    80
#define NTOT    72000      // 57600 + 14400 boxes per image
#define PRE     1000
#define POST    300
#define CAP     4096
#define BCLIP   4.135166556742356f   // log(1000/16)

__device__ __constant__ float c_sizes[9] = {16.f,32.f,64.f,20.f,40.f,80.f,24.f,48.f,96.f};

__device__ inline unsigned fkey(float s) {
    unsigned u = __float_as_uint(s);
    return (u & 0x80000000u) ? ~u : (u | 0x80000000u);
}
__device__ inline float unfkey(unsigned u) {
    return __uint_as_float((u & 0x80000000u) ? (u ^ 0x80000000u) : ~u);
}

// ---------------- kernel A (fused): stream + register argmax ------------------
// One block owns ALL 80 class channels of an 800-cell chunk -> each thread owns
// its 4 cells exclusively: class-max is a register (best, argmax) pair,
// strict-> update (first-max wins = jnp.argmax). Delta channels are NOT read
// here: boxes are decoded only for the top-1000 at gather time (k_sort).
// Coarse 8-bit histogram aggregated in LDS, flushed once per block.
template<int BR>
__device__ inline void fused_impl(int bx, const float* __restrict__ data,
    float* __restrict__ scores, float* __restrict__ cls,
    unsigned* __restrict__ chist, unsigned* lh)
{
    constexpr int ROWF4  = BR ? 400 : 1600;   // channel row length in float4
    constexpr int NQ     = BR ? 2 : 8;        // chunks per row (200 f4 each)

    int slab = bx / NQ;
    int q    = bx - slab * NQ;
    int b = slab / 9, a = slab - (slab / 9) * 9;
    int tid = threadIdx.x;

    if (tid < 200) {
        const float4* d4 = (const float4*)data;
        size_t rowbase = (size_t)(b * 756 + a * 84) * ROWF4 + q * 200;

        float best[4];
        int   bc[4];
        #pragma unroll
        for (int k = 0; k < 4; k++) { best[k] = -INFINITY; bc[k] = 0; }

        // class channels 4..83, batches of 8 (8 loads in flight)
        for (int c0 = 4; c0 < 84; c0 += 8) {
            float4 v[8];
            #pragma unroll
            for (int u = 0; u < 8; u++)
                v[u] = d4[rowbase + (size_t)(c0 + u) * ROWF4 + tid];
            #pragma unroll
            for (int u = 0; u < 8; u++) {
                int c = c0 + u - 4;
                float s0[4];
                *(float4*)s0 = v[u];
                #pragma unroll
                for (int k = 0; k < 4; k++)
                    if (s0[k] > best[k]) { best[k] = s0[k]; bc[k] = c; }
            }
        }

        int ml0 = q * 800 + tid * 4;
        size_t obase = (size_t)b * NTOT + (BR ? (57600 + a * 1600) : (a * 6400));
        size_t o4 = (obase + ml0) >> 2;
        ((float4*)scores)[o4] = make_float4(best[0], best[1], best[2], best[3]);
        ((float4*)cls)[o4]    = make_float4((float)bc[0], (float)bc[1],
                                            (float)bc[2], (float)bc[3]);
        #pragma unroll
        for (int k = 0; k < 4; k++)
            atomicAdd(&lh[fkey(best[k]) >> 24], 1u);
    }
    __syncthreads();
    if (lh[threadIdx.x]) atomicAdd(&chist[b * 256 + threadIdx.x], lh[threadIdx.x]);
}

__global__ __launch_bounds__(256) void k_fused(
    const float* __restrict__ data0, const float* __restrict__ data1,
    float* __restrict__ scores, float* __restrict__ cls,
    unsigned* __restrict__ chist)
{
    __shared__ unsigned lh[256];
    lh[threadIdx.x] = 0;
    __syncthreads();
    int bx = blockIdx.x;
    if (bx < 576) fused_impl<0>(bx, data0, scores, cls, chist, lh);
    else          fused_impl<1>(bx - 576, data1, scores, cls, chist, lh);
}

// ---------------- kernel C2: coarse scan (folded) + fine histogram ------------
__global__ __launch_bounds__(256) void k_fine(const float* __restrict__ scores,
                                              const unsigned* __restrict__ chist,
                                              unsigned* __restrict__ fhist)
{
    __shared__ unsigned S[256];
    __shared__ unsigned lh[256];
    __shared__ unsigned sC;
    int tid = threadIdx.x, b = blockIdx.y;
    S[tid]  = chist[b * 256 + tid];
    lh[tid] = 0;
    __syncthreads();
    for (int off = 1; off < 256; off <<= 1) {   // suffix sum
        unsigned v = S[tid] + ((tid + off < 256) ? S[tid + off] : 0u);
        __syncthreads();
        S[tid] = v;
        __syncthreads();
    }
    if (S[tid] >= (unsigned)PRE && (tid == 255 || S[tid + 1] < (unsigned)PRE)) sC = tid;
    __syncthreads();
    unsigned C = sC;

    int m4 = blockIdx.x * 256 + tid;
    if (m4 < NTOT / 4) {
        float sv[4];
        *(float4*)sv = ((const float4*)(scores + (size_t)b * NTOT))[m4];
        #pragma unroll
        for (int k = 0; k < 4; k++) {
            unsigned u = fkey(sv[k]);
            if ((u >> 24) == C) atomicAdd(&lh[(u >> 16) & 0xFF], 1u);
        }
    }
    __syncthreads();
    if (lh[tid]) atomicAdd(&fhist[b * 256 + tid], lh[tid]);
}

// ---------------- kernel: both scans (folded) + compact >= threshold ----------
__global__ __launch_bounds__(256) void k_compact(const float* __restrict__ scores,
                                                 const unsigned* __restrict__ chist,
                                                 const unsigned* __restrict__ fhist,
                                                 unsigned* __restrict__ cnt,
                                                 unsigned long long* __restrict__ cand)
{
    __shared__ unsigned S[256];
    __shared__ unsigned sC, sCa, sT;
    int tid = threadIdx.x, b = blockIdx.y;

    S[tid] = chist[b * 256 + tid];
    __syncthreads();
    for (int off = 1; off < 256; off <<= 1) {
        unsigned v = S[tid] + ((tid + off < 256) ? S[tid + off] : 0u);
        __syncthreads();
        S[tid] = v;
        __syncthreads();
    }
    if (S[tid] >= (unsigned)PRE && (tid == 255 || S[tid + 1] < (unsigned)PRE)) {
        sC  = tid;
        sCa = (tid == 255) ? 0u : S[tid + 1];
    }
    __syncthreads();
    unsigned C = sC, ca = sCa;
    S[tid] = fhist[b * 256 + tid];
    __syncthreads();
    for (int off = 1; off < 256; off <<= 1) {
        unsigned v = S[tid] + ((tid + off < 256) ? S[tid + off] : 0u);
        __syncthreads();
        S[tid] = v;
        __syncthreads();
    }
    if (ca + S[tid] >= (unsigned)PRE && (tid == 255 || ca + S[tid + 1] < (unsigned)PRE))
        sT = (C << 8) | (unsigned)tid;
    __syncthreads();
    unsigned Tb = sT;

    int m4 = blockIdx.x * 256 + tid;
    if (m4 >= NTOT / 4) return;
    float sv[4];
    *(float4*)sv = ((const float4*)(scores + (size_t)b * NTOT))[m4];
    #pragma unroll
    for (int k = 0; k < 4; k++) {
        unsigned u = fkey(sv[k]);
        if ((u >> 16) >= Tb) {
            int m = m4 * 4 + k;
            int n;
            if (m < 57600) { int a = m / 6400; int hw = m - a * 6400; n = hw * 9 + a; }
            else { int mm = m - 57600; int a = mm / 1600; int hw = mm - a * 1600; n = 57600 + hw * 9 + a; }
            unsigned pos = atomicAdd(&cnt[b], 1u);
            if (pos < CAP)
                cand[(size_t)b * CAP + pos] = ((unsigned long long)u << 32) | (unsigned)(~(unsigned)n);
        }
    }
}

// ---------------- kernel: per-image bitonic sort + decode-gather --------------
// Top-1000 boxes are decoded here from the raw input deltas (4 scattered 4B
// loads each) -- the full 72000-box decode/boxes buffer no longer exists.
__global__ __launch_bounds__(1024) void k_sort(
    const unsigned long long* __restrict__ cand, const unsigned* __restrict__ cnt,
    const float* __restrict__ cls,
    const float* __restrict__ data0, const float* __restrict__ data1,
    float* __restrict__ sboxes, float* __restrict__ sscores, float* __restrict__ scls)
{
    __shared__ unsigned long long keys[CAP];
    int b = blockIdx.x, tid = threadIdx.x;
    int c = min((int)cnt[b], CAP);
    int P = 1024;
    while (P < c) P <<= 1;
    for (int i = tid; i < P; i += 1024)
        keys[i] = (i < c) ? cand[(size_t)b * CAP + i] : 0ULL;

    for (int k2 = 2; k2 <= P; k2 <<= 1)
        for (int j = k2 >> 1; j > 0; j >>= 1) {
            __syncthreads();
            for (int i = tid; i < P; i += 1024) {
                int l = i ^ j;
                if (l > i) {
                    unsigned long long x = keys[i], y = keys[l];
                    bool up = ((i & k2) == 0);
                    if ((x > y) == up) { keys[i] = y; keys[l] = x; }
                }
            }
        }
    __syncthreads();

    if (tid < PRE) {
        unsigned long long key = keys[P - 1 - tid];       // descending
        int n = (int)~(unsigned)(key & 0xFFFFFFFFu);
        int a, hw, W, STRIDE, m;
        const float* dsrc;
        size_t rstride;
        if (n < 57600) {
            hw = n / 9; a = n - hw * 9; m = a * 6400 + hw;
            W = 80; STRIDE = 8; dsrc = data0; rstride = 6400;
        } else {
            int n2 = n - 57600;
            hw = n2 / 9; a = n2 - hw * 9; m = 57600 + a * 1600 + hw;
            W = 40; STRIDE = 16; dsrc = data1; rstride = 1600;
        }
        size_t dbase = (size_t)(b * 756 + a * 84) * rstride + hw;
        float dx = dsrc[dbase];
        float dy = dsrc[dbase + rstride];
        float dw = dsrc[dbase + 2 * rstride];
        float dh = dsrc[dbase + 3 * rstride];

        float sz = c_sizes[a];
        int h = hw / W, w = hw - h * W;
        float cy = (h + 0.5f) * (float)STRIDE;
        float cx = (w + 0.5f) * (float)STRIDE;
        float pcx = dx * sz + cx;
        float pcy = dy * sz + cy;
        float pw  = expf(fminf(dw, BCLIP)) * sz;
        float ph  = expf(fminf(dh, BCLIP)) * sz;
        float x1 = fminf(fmaxf(pcx - 0.5f * pw, 0.f), 640.f);
        float y1 = fminf(fmaxf(pcy - 0.5f * ph, 0.f), 640.f);
        float x2 = fminf(fmaxf(pcx + 0.5f * pw, 0.f), 640.f);
        float y2 = fminf(fmaxf(pcy + 0.5f * ph, 0.f), 640.f);

        ((float4*)sboxes)[b * 1024 + tid] = make_float4(x1, y1, x2, y2);
        sscores[b * 1024 + tid] = unfkey((unsigned)(key >> 32));
        scls[b * 1024 + tid] = cls[(size_t)b * NTOT + m];
    }
}

// ---------------- kernel: IN-suppressor bitmask, transposed layout -------------
// maskT[(b*16 + w)*1024 + j] = bits over ii: box i = w*64+ii suppresses box j
// (i < j, iou > NMS_THR, s_i > s_j).  Lane-contiguous in j: coalesced reads and
// zero cross-lane shuffles in k_nms.
__global__ __launch_bounds__(1024) void k_mask(const float* __restrict__ sboxes,
                                               const float* __restrict__ sscores,
                                               unsigned long long* __restrict__ maskT)
{
    __shared__ float4 bx[64];
    __shared__ float  sl[64];
    int b = blockIdx.y, w = blockIdx.x, tid = threadIdx.x;
    if (tid < 64) {
        int i = w * 64 + tid;
        bx[tid] = ((const float4*)sboxes)[b * 1024 + i];
        sl[tid] = sscores[b * 1024 + i];
    }
    __syncthreads();
    int j = tid;
    unsigned long long* dst = &maskT[((size_t)(b * 16) + w) * 1024 + j];
    if (j >= PRE || w * 64 >= j) { *dst = 0ULL; return; }

    float4 bj = ((const float4*)sboxes)[b * 1024 + j];
    float sj = sscores[b * 1024 + j];
    float areaj = (bj.z - bj.x) * (bj.w - bj.y);
    unsigned long long bits = 0;
    int iend = min(64, j - w * 64);          // suppressors must have i < j
    for (int ii = 0; ii < iend; ii++) {
        float4 bi = bx[ii];
        float ix1 = fmaxf(bi.x, bj.x), iy1 = fmaxf(bi.y, bj.y);
        float ix2 = fminf(bi.z, bj.z), iy2 = fminf(bi.w, bj.w);
        float iw = fmaxf(ix2 - ix1, 0.f), ih = fmaxf(iy2 - iy1, 0.f);
        float inter = iw * ih;
        float areai = (bi.z - bi.x) * (bi.w - bi.y);
        float iou = inter / (areai + areaj - inter + 1e-9f);
        if (iou > 0.5f && sl[ii] > sj) bits |= 1ull << ii;
    }
    *dst = bits;
}

// ---------------- kernel: shuffle-free greedy NMS + output (1 wave / image) ---
// Early exit: output truncates at POST=300 kept boxes; once the running kept
// count reaches 300, remaining chunks provably cannot affect the output
// (kept order = score order; no padding needed when nk >= POST).
__global__ __launch_bounds__(64) void k_nms(const unsigned long long* __restrict__ maskT,
                                            const float* __restrict__ sboxes,
                                            const float* __restrict__ sscores,
                                            const float* __restrict__ scls,
                                            float* __restrict__ out)
{
    int b = blockIdx.x, lane = threadIdx.x;
    const unsigned long long* base = maskT + (size_t)b * 16 * 1024;

    // per-lane validity bit for each chunk (bit c = box c*64+lane valid)
    unsigned validbits = 0;
    #pragma unroll
    for (int c = 0; c < 16; c++) {
        int r = c * 64 + lane;
        bool v = false;
        if (r < PRE) {
            float sc = sscores[b * 1024 + r];
            float4 bbx = ((const float4*)sboxes)[b * 1024 + r];
            v = (sc >= 0.05f) && (bbx.x < bbx.z) && (bbx.y < bbx.w);
        }
        validbits |= (v ? 1u : 0u) << c;
    }

    unsigned long long keptw[16];
    #pragma unroll
    for (int c = 0; c < 16; c++) keptw[c] = 0ULL;

    int total = 0;
    for (int c = 0; c < 16; c++) {
        unsigned long long acc = 0, col = 0;
        #pragma unroll 16
        for (int w = 0; w <= c; w++) {
            unsigned long long m = base[(w << 10) + c * 64 + lane];
            if (w < c) acc |= m & keptw[w];   // suppressed by an earlier kept box?
            else       col = m;               // intra-chunk suppressor column
        }
        bool alive = (((validbits >> c) & 1u) != 0u) && (acc == 0ULL);

        unsigned long long ab = __ballot(alive);
        unsigned long long kw = 0;
        while (ab) {
            int f = __ffsll((unsigned long long)ab) - 1;   // first alive -> kept
            kw |= 1ULL << f;
            alive = alive && (lane != f) && (((col >> f) & 1ULL) == 0ULL);
            ab = __ballot(alive);
        }
        keptw[c] = kw;
        total += __popcll(kw);
        if (total >= POST) break;             // output full: rest is dead work
    }

    __shared__ unsigned long long kws[16];
    __shared__ int pfx[17];
    if (lane == 0) {
        int s = 0;
        #pragma unroll
        for (int w = 0; w < 16; w++) {
            kws[w] = keptw[w];
            pfx[w] = s;
            s += __popcll(keptw[w]);
        }
        pfx[16] = s;
    }
    __syncthreads();
    int nk = pfx[16];

    float* ob = out;                       // [8][300][4]
    float* os = out + BB * POST * 4;       // [8][300]
    float* oc = os + BB * POST;            // [8][300]

    for (int r = lane; r < PRE; r += 64) {
        int w = r >> 6;
        unsigned long long kw = kws[w];
        if ((kw >> (r & 63)) & 1ULL) {
            int rank = pfx[w] + __popcll(kw & ((1ULL << (r & 63)) - 1ULL));
            if (rank < POST) {
                ((float4*)ob)[b * POST + rank] = ((const float4*)sboxes)[b * 1024 + r];
                os[b * POST + rank] = sscores[b * 1024 + r];
                oc[b * POST + rank] = scls[b * 1024 + r];
            }
        }
    }
    for (int p = nk + lane; p < POST; p += 64) {
        ((float4*)ob)[b * POST + p] = make_float4(0.f, 0.f, 0.f, 0.f);
        os[b * POST + p] = 0.f;
        oc[b * POST + p] = 0.f;
    }
}

// ---------------- launch ----------------
extern "C" void kernel_launch(void* const* d_in, const int* in_sizes, int n_in,
                              void* d_out, int out_size, void* d_ws, size_t ws_size,
                              hipStream_t stream)
{
    const float* data0 = (const float*)d_in[0];
    const float* data1 = (const float*)d_in[2];
    for (int i = 0; i < n_in; i++) {
        if (in_sizes[i] == 8 * 756 * 6400) data0 = (const float*)d_in[i];
        else if (in_sizes[i] == 8 * 756 * 1600) data1 = (const float*)d_in[i];
    }

    char* ws = (char*)d_ws;
    size_t off = 0;
    auto alloc = [&](size_t bytes) -> char* {
        char* p = ws + off;
        off = (off + bytes + 255) & ~(size_t)255;
        return p;
    };

    float* scores  = (float*)alloc((size_t)BB * NTOT * 4);
    float* cls     = (float*)alloc((size_t)BB * NTOT * 4);
    // zero-init group (contiguous): cnt(256B pad) + chist(8K) + fhist(8K)
    unsigned* cnt   = (unsigned*)alloc(BB * 4);
    unsigned* chist = (unsigned*)alloc(BB * 256 * 4);
    unsigned* fhist = (unsigned*)alloc(BB * 256 * 4);
    unsigned long long* cand = (unsigned long long*)alloc((size_t)BB * CAP * 8);
    float* sboxes  = (float*)alloc((size_t)BB * 1024 * 4 * 4);
    float* sscores = (float*)alloc((size_t)BB * 1024 * 4);
    float* scls    = (float*)alloc((size_t)BB * 1024 * 4);
    unsigned long long* maskT = (unsigned long long*)alloc((size_t)BB * 16 * 1024 * 8);

    (void)hipMemsetAsync(cnt, 0, 256 + 2 * (size_t)BB * 256 * 4, stream);

    k_fused<<<720, 256, 0, stream>>>(data0, data1, scores, cls, chist);

    dim3 gf((NTOT / 4 + 255) / 256, BB);
    k_fine<<<gf, 256, 0, stream>>>(scores, chist, fhist);

    k_compact<<<gf, 256, 0, stream>>>(scores, chist, fhist, cnt, cand);

    k_sort<<<BB, 1024, 0, stream>>>(cand, cnt, cls, data0, data1,
                                    sboxes, sscores, scls);

    dim3 g5(16, BB);
    k_mask<<<g5, 1024, 0, stream>>>(sboxes, sscores, maskT);

    k_nms<<<BB, 64, 0, stream>>>(maskT, sboxes, sscores, scls, (float*)d_out);
}

// Round 7
// 409.747 us; speedup vs baseline: 1.7132x; 1.0018x over previous
//
#include <hip/hip_runtime.h>
#include <math.h>

// Keep all float arithmetic un-contracted (separate mul/add like the numpy/jax
// f32 reference) so discrete decisions (argmax, top-k order, iou>thr) match.
#pragma clang fp contract(off)

// ---------------- problem constants ----------------
#define BB      8
#define AA      9
#define NCLS    80
#define NTOT    72000      // 57600 + 14400 boxes per image
#define PRE     1000
#define POST    300
#define CAP     4096
#define BCLIP   4.135166556742356f   // log(1000/16)

__device__ __constant__ float c_sizes[9] = {16.f,32.f,64.f,20.f,40.f,80.f,24.f,48.f,96.f};

__device__ inline unsigned fkey(float s) {
    unsigned u = __float_as_uint(s);
    return (u & 0x80000000u) ? ~u : (u | 0x80000000u);
}
__device__ inline float unfkey(unsigned u) {
    return __uint_as_float((u & 0x80000000u) ? (u ^ 0x80000000u) : ~u);
}

// ---------------- kernel A (fused): stream + register argmax ------------------
// One block owns ALL 80 class channels of an 800-cell chunk -> each thread owns
// its 4 cells exclusively: class-max is a register (best, argmax) pair,
// strict-> update (first-max wins = jnp.argmax). Delta channels are NOT read
// here: boxes are decoded only for the top-1000 at gather time (k_sort).
// 16 float4 loads in flight per batch (grid-limited occupancy 2.8 blocks/CU ->
// deep per-thread MLP is the latency-hiding lever). cls stored as u8.
template<int BR>
__device__ inline void fused_impl(int bx, const float* __restrict__ data,
    float* __restrict__ scores, unsigned char* __restrict__ cls,
    unsigned* __restrict__ chist, unsigned* lh)
{
    constexpr int ROWF4  = BR ? 400 : 1600;   // channel row length in float4
    constexpr int NQ     = BR ? 2 : 8;        // chunks per row (200 f4 each)

    int slab = bx / NQ;
    int q    = bx - slab * NQ;
    int b = slab / 9, a = slab - (slab / 9) * 9;
    int tid = threadIdx.x;

    if (tid < 200) {
        const float4* d4 = (const float4*)data;
        size_t rowbase = (size_t)(b * 756 + a * 84) * ROWF4 + q * 200;

        float best[4];
        int   bc[4];
        #pragma unroll
        for (int k = 0; k < 4; k++) { best[k] = -INFINITY; bc[k] = 0; }

        // class channels 4..83, batches of 16 (16 loads in flight)
        for (int c0 = 4; c0 < 84; c0 += 16) {
            float4 v[16];
            #pragma unroll
            for (int u = 0; u < 16; u++)
                v[u] = d4[rowbase + (size_t)(c0 + u) * ROWF4 + tid];
            #pragma unroll
            for (int u = 0; u < 16; u++) {
                int c = c0 + u - 4;
                float s0[4];
                *(float4*)s0 = v[u];
                #pragma unroll
                for (int k = 0; k < 4; k++)
                    if (s0[k] > best[k]) { best[k] = s0[k]; bc[k] = c; }
            }
        }

        int ml0 = q * 800 + tid * 4;
        size_t obase = (size_t)b * NTOT + (BR ? (57600 + a * 1600) : (a * 6400));
        size_t o4 = (obase + ml0) >> 2;
        ((float4*)scores)[o4] = make_float4(best[0], best[1], best[2], best[3]);
        ((uchar4*)cls)[o4]    = make_uchar4((unsigned char)bc[0], (unsigned char)bc[1],
                                            (unsigned char)bc[2], (unsigned char)bc[3]);
        #pragma unroll
        for (int k = 0; k < 4; k++)
            atomicAdd(&lh[fkey(best[k]) >> 24], 1u);
    }
    __syncthreads();
    if (lh[threadIdx.x]) atomicAdd(&chist[b * 256 + threadIdx.x], lh[threadIdx.x]);
}

__global__ __launch_bounds__(256) void k_fused(
    const float* __restrict__ data0, const float* __restrict__ data1,
    float* __restrict__ scores, unsigned char* __restrict__ cls,
    unsigned* __restrict__ chist)
{
    __shared__ unsigned lh[256];
    lh[threadIdx.x] = 0;
    __syncthreads();
    int bx = blockIdx.x;
    if (bx < 576) fused_impl<0>(bx, data0, scores, cls, chist, lh);
    else          fused_impl<1>(bx - 576, data1, scores, cls, chist, lh);
}

// ---------------- kernel C2: coarse scan (folded) + fine histogram ------------
__global__ __launch_bounds__(256) void k_fine(const float* __restrict__ scores,
                                              const unsigned* __restrict__ chist,
                                              unsigned* __restrict__ fhist)
{
    __shared__ unsigned S[256];
    __shared__ unsigned lh[256];
    __shared__ unsigned sC;
    int tid = threadIdx.x, b = blockIdx.y;
    S[tid]  = chist[b * 256 + tid];
    lh[tid] = 0;
    __syncthreads();
    for (int off = 1; off < 256; off <<= 1) {   // suffix sum
        unsigned v = S[tid] + ((tid + off < 256) ? S[tid + off] : 0u);
        __syncthreads();
        S[tid] = v;
        __syncthreads();
    }
    if (S[tid] >= (unsigned)PRE && (tid == 255 || S[tid + 1] < (unsigned)PRE)) sC = tid;
    __syncthreads();
    unsigned C = sC;

    int m4 = blockIdx.x * 256 + tid;
    if (m4 < NTOT / 4) {
        float sv[4];
        *(float4*)sv = ((const float4*)(scores + (size_t)b * NTOT))[m4];
        #pragma unroll
        for (int k = 0; k < 4; k++) {
            unsigned u = fkey(sv[k]);
            if ((u >> 24) == C) atomicAdd(&lh[(u >> 16) & 0xFF], 1u);
        }
    }
    __syncthreads();
    if (lh[tid]) atomicAdd(&fhist[b * 256 + tid], lh[tid]);
}

// ---------------- kernel: both scans (folded) + compact >= threshold ----------
__global__ __launch_bounds__(256) void k_compact(const float* __restrict__ scores,
                                                 const unsigned* __restrict__ chist,
                                                 const unsigned* __restrict__ fhist,
                                                 unsigned* __restrict__ cnt,
                                                 unsigned long long* __restrict__ cand)
{
    __shared__ unsigned S[256];
    __shared__ unsigned sC, sCa, sT;
    int tid = threadIdx.x, b = blockIdx.y;

    S[tid] = chist[b * 256 + tid];
    __syncthreads();
    for (int off = 1; off < 256; off <<= 1) {
        unsigned v = S[tid] + ((tid + off < 256) ? S[tid + off] : 0u);
        __syncthreads();
        S[tid] = v;
        __syncthreads();
    }
    if (S[tid] >= (unsigned)PRE && (tid == 255 || S[tid + 1] < (unsigned)PRE)) {
        sC  = tid;
        sCa = (tid == 255) ? 0u : S[tid + 1];
    }
    __syncthreads();
    unsigned C = sC, ca = sCa;
    S[tid] = fhist[b * 256 + tid];
    __syncthreads();
    for (int off = 1; off < 256; off <<= 1) {
        unsigned v = S[tid] + ((tid + off < 256) ? S[tid + off] : 0u);
        __syncthreads();
        S[tid] = v;
        __syncthreads();
    }
    if (ca + S[tid] >= (unsigned)PRE && (tid == 255 || ca + S[tid + 1] < (unsigned)PRE))
        sT = (C << 8) | (unsigned)tid;
    __syncthreads();
    unsigned Tb = sT;

    int m4 = blockIdx.x * 256 + tid;
    if (m4 >= NTOT / 4) return;
    float sv[4];
    *(float4*)sv = ((const float4*)(scores + (size_t)b * NTOT))[m4];
    #pragma unroll
    for (int k = 0; k < 4; k++) {
        unsigned u = fkey(sv[k]);
        if ((u >> 16) >= Tb) {
            int m = m4 * 4 + k;
            int n;
            if (m < 57600) { int a = m / 6400; int hw = m - a * 6400; n = hw * 9 + a; }
            else { int mm = m - 57600; int a = mm / 1600; int hw = mm - a * 1600; n = 57600 + hw * 9 + a; }
            unsigned pos = atomicAdd(&cnt[b], 1u);
            if (pos < CAP)
                cand[(size_t)b * CAP + pos] = ((unsigned long long)u << 32) | (unsigned)(~(unsigned)n);
        }
    }
}

// ---------------- kernel: per-image bitonic sort + decode-gather --------------
// Top-1000 boxes are decoded here from the raw input deltas (4 scattered 4B
// loads each) -- the full 72000-box decode/boxes buffer no longer exists.
__global__ __launch_bounds__(1024) void k_sort(
    const unsigned long long* __restrict__ cand, const unsigned* __restrict__ cnt,
    const unsigned char* __restrict__ cls,
    const float* __restrict__ data0, const float* __restrict__ data1,
    float* __restrict__ sboxes, float* __restrict__ sscores, float* __restrict__ scls)
{
    __shared__ unsigned long long keys[CAP];
    int b = blockIdx.x, tid = threadIdx.x;
    int c = min((int)cnt[b], CAP);
    int P = 1024;
    while (P < c) P <<= 1;
    for (int i = tid; i < P; i += 1024)
        keys[i] = (i < c) ? cand[(size_t)b * CAP + i] : 0ULL;

    for (int k2 = 2; k2 <= P; k2 <<= 1)
        for (int j = k2 >> 1; j > 0; j >>= 1) {
            __syncthreads();
            for (int i = tid; i < P; i += 1024) {
                int l = i ^ j;
                if (l > i) {
                    unsigned long long x = keys[i], y = keys[l];
                    bool up = ((i & k2) == 0);
                    if ((x > y) == up) { keys[i] = y; keys[l] = x; }
                }
            }
        }
    __syncthreads();

    if (tid < PRE) {
        unsigned long long key = keys[P - 1 - tid];       // descending
        int n = (int)~(unsigned)(key & 0xFFFFFFFFu);
        int a, hw, W, STRIDE, m;
        const float* dsrc;
        size_t rstride;
        if (n < 57600) {
            hw = n / 9; a = n - hw * 9; m = a * 6400 + hw;
            W = 80; STRIDE = 8; dsrc = data0; rstride = 6400;
        } else {
            int n2 = n - 57600;
            hw = n2 / 9; a = n2 - hw * 9; m = 57600 + a * 1600 + hw;
            W = 40; STRIDE = 16; dsrc = data1; rstride = 1600;
        }
        size_t dbase = (size_t)(b * 756 + a * 84) * rstride + hw;
        float dx = dsrc[dbase];
        float dy = dsrc[dbase + rstride];
        float dw = dsrc[dbase + 2 * rstride];
        float dh = dsrc[dbase + 3 * rstride];

        float sz = c_sizes[a];
        int h = hw / W, w = hw - h * W;
        float cy = (h + 0.5f) * (float)STRIDE;
        float cx = (w + 0.5f) * (float)STRIDE;
        float pcx = dx * sz + cx;
        float pcy = dy * sz + cy;
        float pw  = expf(fminf(dw, BCLIP)) * sz;
        float ph  = expf(fminf(dh, BCLIP)) * sz;
        float x1 = fminf(fmaxf(pcx - 0.5f * pw, 0.f), 640.f);
        float y1 = fminf(fmaxf(pcy - 0.5f * ph, 0.f), 640.f);
        float x2 = fminf(fmaxf(pcx + 0.5f * pw, 0.f), 640.f);
        float y2 = fminf(fmaxf(pcy + 0.5f * ph, 0.f), 640.f);

        ((float4*)sboxes)[b * 1024 + tid] = make_float4(x1, y1, x2, y2);
        sscores[b * 1024 + tid] = unfkey((unsigned)(key >> 32));
        scls[b * 1024 + tid] = (float)cls[(size_t)b * NTOT + m];
    }
}

// ---------------- kernel: IN-suppressor bitmask, transposed layout -------------
// maskT[(b*16 + w)*1024 + j] = bits over ii: box i = w*64+ii suppresses box j
// (i < j, iou > NMS_THR, s_i > s_j).  Lane-contiguous in j: coalesced reads and
// zero cross-lane shuffles in k_nms.
__global__ __launch_bounds__(1024) void k_mask(const float* __restrict__ sboxes,
                                               const float* __restrict__ sscores,
                                               unsigned long long* __restrict__ maskT)
{
    __shared__ float4 bx[64];
    __shared__ float  sl[64];
    int b = blockIdx.y, w = blockIdx.x, tid = threadIdx.x;
    if (tid < 64) {
        int i = w * 64 + tid;
        bx[tid] = ((const float4*)sboxes)[b * 1024 + i];
        sl[tid] = sscores[b * 1024 + i];
    }
    __syncthreads();
    int j = tid;
    unsigned long long* dst = &maskT[((size_t)(b * 16) + w) * 1024 + j];
    if (j >= PRE || w * 64 >= j) { *dst = 0ULL; return; }

    float4 bj = ((const float4*)sboxes)[b * 1024 + j];
    float sj = sscores[b * 1024 + j];
    float areaj = (bj.z - bj.x) * (bj.w - bj.y);
    unsigned long long bits = 0;
    int iend = min(64, j - w * 64);          // suppressors must have i < j
    for (int ii = 0; ii < iend; ii++) {
        float4 bi = bx[ii];
        float ix1 = fmaxf(bi.x, bj.x), iy1 = fmaxf(bi.y, bj.y);
        float ix2 = fminf(bi.z, bj.z), iy2 = fminf(bi.w, bj.w);
        float iw = fmaxf(ix2 - ix1, 0.f), ih = fmaxf(iy2 - iy1, 0.f);
        float inter = iw * ih;
        float areai = (bi.z - bi.x) * (bi.w - bi.y);
        float iou = inter / (areai + areaj - inter + 1e-9f);
        if (iou > 0.5f && sl[ii] > sj) bits |= 1ull << ii;
    }
    *dst = bits;
}

// ---------------- kernel: shuffle-free greedy NMS + output (1 wave / image) ---
// Early exit: output truncates at POST=300 kept boxes; once the running kept
// count reaches 300, remaining chunks provably cannot affect the output
// (kept order = score order; no padding needed when nk >= POST).
__global__ __launch_bounds__(64) void k_nms(const unsigned long long* __restrict__ maskT,
                                            const float* __restrict__ sboxes,
                                            const float* __restrict__ sscores,
                                            const float* __restrict__ scls,
                                            float* __restrict__ out)
{
    int b = blockIdx.x, lane = threadIdx.x;
    const unsigned long long* base = maskT + (size_t)b * 16 * 1024;

    // per-lane validity bit for each chunk (bit c = box c*64+lane valid)
    unsigned validbits = 0;
    #pragma unroll
    for (int c = 0; c < 16; c++) {
        int r = c * 64 + lane;
        bool v = false;
        if (r < PRE) {
            float sc = sscores[b * 1024 + r];
            float4 bbx = ((const float4*)sboxes)[b * 1024 + r];
            v = (sc >= 0.05f) && (bbx.x < bbx.z) && (bbx.y < bbx.w);
        }
        validbits |= (v ? 1u : 0u) << c;
    }

    unsigned long long keptw[16];
    #pragma unroll
    for (int c = 0; c < 16; c++) keptw[c] = 0ULL;

    int total = 0;
    for (int c = 0; c < 16; c++) {
        unsigned long long acc = 0, col = 0;
        #pragma unroll 16
        for (int w = 0; w <= c; w++) {
            unsigned long long m = base[(w << 10) + c * 64 + lane];
            if (w < c) acc |= m & keptw[w];   // suppressed by an earlier kept box?
            else       col = m;               // intra-chunk suppressor column
        }
        bool alive = (((validbits >> c) & 1u) != 0u) && (acc == 0ULL);

        unsigned long long ab = __ballot(alive);
        unsigned long long kw = 0;
        while (ab) {
            int f = __ffsll((unsigned long long)ab) - 1;   // first alive -> kept
            kw |= 1ULL << f;
            alive = alive && (lane != f) && (((col >> f) & 1ULL) == 0ULL);
            ab = __ballot(alive);
        }
        keptw[c] = kw;
        total += __popcll(kw);
        if (total >= POST) break;             // output full: rest is dead work
    }

    __shared__ unsigned long long kws[16];
    __shared__ int pfx[17];
    if (lane == 0) {
        int s = 0;
        #pragma unroll
        for (int w = 0; w < 16; w++) {
            kws[w] = keptw[w];
            pfx[w] = s;
            s += __popcll(keptw[w]);
        }
        pfx[16] = s;
    }
    __syncthreads();
    int nk = pfx[16];

    float* ob = out;                       // [8][300][4]
    float* os = out + BB * POST * 4;       // [8][300]
    float* oc = os + BB * POST;            // [8][300]

    for (int r = lane; r < PRE; r += 64) {
        int w = r >> 6;
        unsigned long long kw = kws[w];
        if ((kw >> (r & 63)) & 1ULL) {
            int rank = pfx[w] + __popcll(kw & ((1ULL << (r & 63)) - 1ULL));
            if (rank < POST) {
                ((float4*)ob)[b * POST + rank] = ((const float4*)sboxes)[b * 1024 + r];
                os[b * POST + rank] = sscores[b * 1024 + r];
                oc[b * POST + rank] = scls[b * 1024 + r];
            }
        }
    }
    for (int p = nk + lane; p < POST; p += 64) {
        ((float4*)ob)[b * POST + p] = make_float4(0.f, 0.f, 0.f, 0.f);
        os[b * POST + p] = 0.f;
        oc[b * POST + p] = 0.f;
    }
}

// ---------------- launch ----------------
extern "C" void kernel_launch(void* const* d_in, const int* in_sizes, int n_in,
                              void* d_out, int out_size, void* d_ws, size_t ws_size,
                              hipStream_t stream)
{
    const float* data0 = (const float*)d_in[0];
    const float* data1 = (const float*)d_in[2];
    for (int i = 0; i < n_in; i++) {
        if (in_sizes[i] == 8 * 756 * 6400) data0 = (const float*)d_in[i];
        else if (in_sizes[i] == 8 * 756 * 1600) data1 = (const float*)d_in[i];
    }

    char* ws = (char*)d_ws;
    size_t off = 0;
    auto alloc = [&](size_t bytes) -> char* {
        char* p = ws + off;
        off = (off + bytes + 255) & ~(size_t)255;
        return p;
    };

    float* scores  = (float*)alloc((size_t)BB * NTOT * 4);
    unsigned char* cls = (unsigned char*)alloc((size_t)BB * NTOT);
    // zero-init group (contiguous): cnt(256B pad) + chist(8K) + fhist(8K)
    unsigned* cnt   = (unsigned*)alloc(BB * 4);
    unsigned* chist = (unsigned*)alloc(BB * 256 * 4);
    unsigned* fhist = (unsigned*)alloc(BB * 256 * 4);
    unsigned long long* cand = (unsigned long long*)alloc((size_t)BB * CAP * 8);
    float* sboxes  = (float*)alloc((size_t)BB * 1024 * 4 * 4);
    float* sscores = (float*)alloc((size_t)BB * 1024 * 4);
    float* scls    = (float*)alloc((size_t)BB * 1024 * 4);
    unsigned long long* maskT = (unsigned long long*)alloc((size_t)BB * 16 * 1024 * 8);

    (void)hipMemsetAsync(cnt, 0, 256 + 2 * (size_t)BB * 256 * 4, stream);

    k_fused<<<720, 256, 0, stream>>>(data0, data1, scores, cls, chist);

    dim3 gf((NTOT / 4 + 255) / 256, BB);
    k_fine<<<gf, 256, 0, stream>>>(scores, chist, fhist);

    k_compact<<<gf, 256, 0, stream>>>(scores, chist, fhist, cnt, cand);

    k_sort<<<BB, 1024, 0, stream>>>(cand, cnt, cls, data0, data1,
                                    sboxes, sscores, scls);

    dim3 g5(16, BB);
    k_mask<<<g5, 1024, 0, stream>>>(sboxes, sscores, maskT);

    k_nms<<<BB, 64, 0, stream>>>(maskT, sboxes, sscores, scls, (float*)d_out);
}